// Round 12
// baseline (29.275 us; speedup 1.0000x reference)
//
#include <hip/hip_runtime.h>
#include <math.h>

#define FDIM  50
#define EDIM  16
#define ADIM  16
#define NPAIR 1225
#define BROWS 32        // batch rows per block (MFMA cols)
#define NTHREADS 768
#define NWAVE 12
#define NST   24        // independent pair streams: 2 per wave
#define KITER 51        // common iterations: p = s + 24k, k<51; +1 tail pair (1224)
#define NPAD  1248      // ij table padded for next-iter prefetch reads
#define FBLK  1024      // bytes per f-row in LDS: [lane64][16B]

typedef _Float16 half8v __attribute__((ext_vector_type(8)));
typedef __fp16   h16x8  __attribute__((ext_vector_type(8)));
typedef __fp16   h16x2  __attribute__((ext_vector_type(2)));
typedef float    f32x16 __attribute__((ext_vector_type(16)));

__device__ inline f32x16 mfma32x32x16f16(half8v a, half8v b, f32x16 c) {
    return __builtin_amdgcn_mfma_f32_32x32x16_f16(
        __builtin_bit_cast(h16x8, a), __builtin_bit_cast(h16x8, b), c, 0, 0, 0);
}

__global__ __launch_bounds__(NTHREADS) void afm_fwd(
    const int*   __restrict__ feat_index,
    const float* __restrict__ feat_value,
    const float* __restrict__ emb_table,
    const float* __restrict__ attn_w,
    const float* __restrict__ attn_b,
    const float* __restrict__ attn_h,
    const float* __restrict__ attn_p,
    const float* __restrict__ lin_w,
    const float* __restrict__ lin_b,
    float*       __restrict__ out)
{
    // [f][lane64][8 f16]: lane = kh*32 + b, holds e = kh*8..kh*8+7 for batch col b
    __shared__ __align__(16) _Float16 embLds[FDIM * 512];   // 51200 B
    __shared__ unsigned ijLds[NPAD];                        // (i*FBLK)<<16 | j*FBLK
    __shared__ float redLds[NWAVE][BROWS][2];               // [wv][b][{num,den}]
    __shared__ float ylinLds[BROWS];
    __shared__ float lwLds[FDIM];

    const int t    = threadIdx.x;
    const int lane = t & 63;
    const int wv   = t >> 6;
    const int hi   = lane >> 5;    // k-half (and num/den role)
    const int col  = lane & 31;    // batch col (B) / D-row index for A
    const int b0   = blockIdx.x * BROWS;

    if (t < FDIM) lwLds[t] = lin_w[t];

    // ---- ij offset table (padded; tail repeats last pair) ----
    for (int p = t; p < NPAD; p += NTHREADS) {
        int pc = (p < NPAIR) ? p : NPAIR - 1;
        float tq = 9801.0f - 8.0f * (float)pc;
        int ii = (int)((99.0f - sqrtf(tq)) * 0.5f);
        ii = max(0, min(48, ii));
        while (ii < 48 && (49*(ii+1) - (((ii+1)*ii)>>1)) <= pc) ++ii;
        while (ii > 0  && (49*ii - ((ii*(ii-1))>>1)) > pc) --ii;
        int q  = 49*ii - ((ii*(ii-1))>>1);
        int jj = ii + 1 + (pc - q);
        ijLds[p] = ((unsigned)(ii*FBLK) << 16) | (unsigned)(jj*FBLK);
    }

    // ---- stage emb: lane l -> (b=l&31, kh=l>>5) ----
    for (int f = t >> 6; f < FDIM; f += NWAVE) {
        int   fi = feat_index[(b0 + col) * FDIM + f];
        float fv = feat_value[(b0 + col) * FDIM + f];
        const float4* tr = (const float4*)(emb_table + (size_t)fi * EDIM + hi * 8);
        float4 v0 = tr[0], v1 = tr[1];
        half8v hh;
        hh[0] = (_Float16)(v0.x * fv); hh[1] = (_Float16)(v0.y * fv);
        hh[2] = (_Float16)(v0.z * fv); hh[3] = (_Float16)(v0.w * fv);
        hh[4] = (_Float16)(v1.x * fv); hh[5] = (_Float16)(v1.y * fv);
        hh[6] = (_Float16)(v1.z * fv); hh[7] = (_Float16)(v1.w * fv);
        *(half8v*)&embLds[f * 512 + lane * 8] = hh;
    }
    __syncthreads();

    // ---- y_lin: threads 0..511: b = t>>4, e = t&15 ----
    if (t < 512) {
        int bb = t >> 4, e = t & 15;
        int off = (e >> 3) * 256 + bb * 8 + (e & 7);
        float acc = lin_b[0];
        #pragma unroll
        for (int f = 0; f < FDIM; ++f)
            acc = fmaf((float)embLds[f * 512 + off], lwLds[f], acc);
        acc = fmaxf(acc, 0.0f);
        acc += __shfl_xor(acc, 1);
        acc += __shfl_xor(acc, 2);
        acc += __shfl_xor(acc, 4);
        acc += __shfl_xor(acc, 8);
        if (e == 0) ylinLds[bb] = acc;
    }

    // ---- loop-invariant fragments ----
    // MFMA1: D[m][b] = sum_e A[m][e]*ewp[e][b] (+C). A rows: m<16 -> W^T, m==16 -> p, else 0.
    half8v fragA1;
    #pragma unroll
    for (int e = 0; e < 8; ++e) {
        int k = hi * 8 + e;
        float av = (col < ADIM) ? attn_w[k * ADIM + col]
                 : (col == ADIM) ? attn_p[k] : 0.0f;
        fragA1[e] = (_Float16)av;
    }
    // C/D row map: reg r (0..7) holds row (r&3)+8*(r>>2)+4*hi.
    // MFMA2: B2 elem e (k=hi*8+e) = packed relu(acc1[e]) = P[pi(k)][b],
    //        pi(k) = (e&3)+8*(e>>2)+4*hi -> A2[m][k] = h[pi(k)]*log2e for all m.
    // MFMA2 reuses biasC as C (saves 16 zero regs): acc2[0] = s + attn_b[4*hi];
    // the constant factor 2^attn_b[4*hi] on every sc is removed at the epilogue.
    half8v fragA2;
    f32x16 biasC;
    #pragma unroll
    for (int e = 0; e < 8; ++e) {
        int r = (e & 3) + 8 * (e >> 2) + 4 * hi;
        fragA2[e]  = (_Float16)(attn_h[r] * 1.44269504f);
        biasC[e]   = attn_b[r];
        biasC[e+8] = 0.f;
    }
    const float corr = __builtin_amdgcn_exp2f(-attn_b[4 * hi]);

    const char* ebase = (const char*)embLds;
    const unsigned laddr = (unsigned)lane * 16u;

    // ---- two independent pair streams per wave: pA = 2wv + 24k, pB = 2wv+1 + 24k ----
    const int s0 = wv * 2;
    unsigned uA = ijLds[s0];
    unsigned uB = ijLds[s0 + 1];
    float numA = 0.f, denA = 0.f, numB = 0.f, denB = 0.f;

    for (int k = 0; k < KITER; ++k) {
        half8v eiA = *(const half8v*)(ebase + (uA >> 16)     + laddr);
        half8v ejA = *(const half8v*)(ebase + (uA & 0xffffu) + laddr);
        half8v eiB = *(const half8v*)(ebase + (uB >> 16)     + laddr);
        half8v ejB = *(const half8v*)(ebase + (uB & 0xffffu) + laddr);
        int nidx = s0 + NST * (k + 1);
        uA = ijLds[nidx];
        uB = ijLds[nidx + 1];

        // ---- stream A ----
        {
            half8v prod = eiA * ejA;
            f32x16 acc1 = mfma32x32x16f16(fragA1, prod, biasC);
            h16x2 q01 = __builtin_amdgcn_cvt_pkrtz(acc1[0], acc1[1]);
            h16x2 q23 = __builtin_amdgcn_cvt_pkrtz(acc1[2], acc1[3]);
            h16x2 q45 = __builtin_amdgcn_cvt_pkrtz(acc1[4], acc1[5]);
            h16x2 q67 = __builtin_amdgcn_cvt_pkrtz(acc1[6], acc1[7]);
            h16x8 pk = __builtin_shufflevector(
                           __builtin_shufflevector(q01, q23, 0, 1, 2, 3),
                           __builtin_shufflevector(q45, q67, 0, 1, 2, 3),
                           0, 1, 2, 3, 4, 5, 6, 7);
            half8v rf = __builtin_bit_cast(half8v, pk);
            half8v zf;
            #pragma unroll
            for (int e = 0; e < 8; ++e) zf[e] = (_Float16)0;
            rf = __builtin_elementwise_max(rf, zf);
            f32x16 acc2 = mfma32x32x16f16(fragA2, rf, biasC);
            float sc = __builtin_amdgcn_exp2f(acc2[0]);
            denA += sc;                              // valid on hi=1 lanes
            numA = fmaf(sc, acc1[8], numA);          // acc1[8]=u (hi=0); =0 (hi=1)
        }
        // ---- stream B ----
        {
            half8v prod = eiB * ejB;
            f32x16 acc1 = mfma32x32x16f16(fragA1, prod, biasC);
            h16x2 q01 = __builtin_amdgcn_cvt_pkrtz(acc1[0], acc1[1]);
            h16x2 q23 = __builtin_amdgcn_cvt_pkrtz(acc1[2], acc1[3]);
            h16x2 q45 = __builtin_amdgcn_cvt_pkrtz(acc1[4], acc1[5]);
            h16x2 q67 = __builtin_amdgcn_cvt_pkrtz(acc1[6], acc1[7]);
            h16x8 pk = __builtin_shufflevector(
                           __builtin_shufflevector(q01, q23, 0, 1, 2, 3),
                           __builtin_shufflevector(q45, q67, 0, 1, 2, 3),
                           0, 1, 2, 3, 4, 5, 6, 7);
            half8v rf = __builtin_bit_cast(half8v, pk);
            half8v zf;
            #pragma unroll
            for (int e = 0; e < 8; ++e) zf[e] = (_Float16)0;
            rf = __builtin_elementwise_max(rf, zf);
            f32x16 acc2 = mfma32x32x16f16(fragA2, rf, biasC);
            float sc = __builtin_amdgcn_exp2f(acc2[0]);
            denB += sc;
            numB = fmaf(sc, acc1[8], numB);
        }
    }

    // tail: pair 1224 = 0 + 24*51, owned by wave 0 stream A (uA == ijLds[1224])
    if (wv == 0) {
        half8v eiA = *(const half8v*)(ebase + (uA >> 16)     + laddr);
        half8v ejA = *(const half8v*)(ebase + (uA & 0xffffu) + laddr);
        half8v prod = eiA * ejA;
        f32x16 acc1 = mfma32x32x16f16(fragA1, prod, biasC);
        h16x2 q01 = __builtin_amdgcn_cvt_pkrtz(acc1[0], acc1[1]);
        h16x2 q23 = __builtin_amdgcn_cvt_pkrtz(acc1[2], acc1[3]);
        h16x2 q45 = __builtin_amdgcn_cvt_pkrtz(acc1[4], acc1[5]);
        h16x2 q67 = __builtin_amdgcn_cvt_pkrtz(acc1[6], acc1[7]);
        h16x8 pk = __builtin_shufflevector(
                       __builtin_shufflevector(q01, q23, 0, 1, 2, 3),
                       __builtin_shufflevector(q45, q67, 0, 1, 2, 3),
                       0, 1, 2, 3, 4, 5, 6, 7);
        half8v rf = __builtin_bit_cast(half8v, pk);
        half8v zf;
        #pragma unroll
        for (int e = 0; e < 8; ++e) zf[e] = (_Float16)0;
        rf = __builtin_elementwise_max(rf, zf);
        f32x16 acc2 = mfma32x32x16f16(fragA2, rf, biasC);
        float sc = __builtin_amdgcn_exp2f(acc2[0]);
        denA += sc;
        numA = fmaf(sc, acc1[8], numA);
    }

    float num = (numA + numB) * corr;   // undo the 2^attn_b[4hi] factor
    float den = (denA + denB) * corr;
    if (hi) redLds[wv][col][1] = den;   // hi=1 lanes: true denominator
    else    redLds[wv][col][0] = num;   // hi=0 lanes: true numerator
    __syncthreads();

    if (t < BROWS) {
        float nn = 0.f, dd = 0.f;
        #pragma unroll
        for (int w = 0; w < NWAVE; ++w) { nn += redLds[w][t][0]; dd += redLds[w][t][1]; }
        out[b0 + t] = nn / dd + ylinLds[t];
    }
}

extern "C" void kernel_launch(void* const* d_in, const int* in_sizes, int n_in,
                              void* d_out, int out_size, void* d_ws, size_t ws_size,
                              hipStream_t stream) {
    const int*   feat_index = (const int*)  d_in[0];
    const float* feat_value = (const float*)d_in[1];
    const float* emb_table  = (const float*)d_in[2];
    const float* attn_w     = (const float*)d_in[3];
    const float* attn_b     = (const float*)d_in[4];
    const float* attn_h     = (const float*)d_in[5];
    const float* attn_p     = (const float*)d_in[6];
    const float* lin_w      = (const float*)d_in[7];
    const float* lin_b      = (const float*)d_in[8];
    float* outp = (float*)d_out;

    dim3 grid(out_size / BROWS);   // 256 blocks of 32 batch rows
    dim3 block(NTHREADS);
    afm_fwd<<<grid, block, 0, stream>>>(feat_index, feat_value, emb_table,
                                        attn_w, attn_b, attn_h, attn_p,
                                        lin_w, lin_b, outp);
}

// Round 13
// 28.316 us; speedup vs baseline: 1.0338x; 1.0338x over previous
//
#include <hip/hip_runtime.h>
#include <math.h>

#define FDIM  50
#define EDIM  16
#define ADIM  16
#define NPAIR 1225
#define BROWS 32        // batch rows per block (MFMA cols)
#define NTHREADS 1024
#define NWAVE 16
#define CHUNK 77        // contiguous pairs per wave (last wave: 70)
#define FBLK  1024      // bytes per f-row in LDS: [lane64][16B]

typedef _Float16 half8v __attribute__((ext_vector_type(8)));
typedef __fp16   h16x8  __attribute__((ext_vector_type(8)));
typedef __fp16   h16x2  __attribute__((ext_vector_type(2)));
typedef float    f32x16 __attribute__((ext_vector_type(16)));

__device__ inline f32x16 mfma32x32x16f16(half8v a, half8v b, f32x16 c) {
    return __builtin_amdgcn_mfma_f32_32x32x16_f16(
        __builtin_bit_cast(h16x8, a), __builtin_bit_cast(h16x8, b), c, 0, 0, 0);
}

__device__ inline half8v relu_pack(const f32x16& acc1) {
    h16x2 q01 = __builtin_amdgcn_cvt_pkrtz(acc1[0], acc1[1]);
    h16x2 q23 = __builtin_amdgcn_cvt_pkrtz(acc1[2], acc1[3]);
    h16x2 q45 = __builtin_amdgcn_cvt_pkrtz(acc1[4], acc1[5]);
    h16x2 q67 = __builtin_amdgcn_cvt_pkrtz(acc1[6], acc1[7]);
    h16x8 pk = __builtin_shufflevector(
                   __builtin_shufflevector(q01, q23, 0, 1, 2, 3),
                   __builtin_shufflevector(q45, q67, 0, 1, 2, 3),
                   0, 1, 2, 3, 4, 5, 6, 7);
    half8v rf = __builtin_bit_cast(half8v, pk);
    half8v zf;
    #pragma unroll
    for (int e = 0; e < 8; ++e) zf[e] = (_Float16)0;
    return __builtin_elementwise_max(rf, zf);
}

__global__ __launch_bounds__(NTHREADS) void afm_fwd(
    const int*   __restrict__ feat_index,
    const float* __restrict__ feat_value,
    const float* __restrict__ emb_table,
    const float* __restrict__ attn_w,
    const float* __restrict__ attn_b,
    const float* __restrict__ attn_h,
    const float* __restrict__ attn_p,
    const float* __restrict__ lin_w,
    const float* __restrict__ lin_b,
    float*       __restrict__ out)
{
    // [f][lane64][8 f16]: lane = kh*32 + b, holds e = kh*8..kh*8+7 for batch col b
    // +1 zeroed pad row (f=50) for the dual-j overread
    __shared__ __align__(16) _Float16 embLds[(FDIM + 1) * 512];   // 52224 B
    __shared__ float redLds[NWAVE][BROWS][2];                     // [wv][b][{num,den}]
    __shared__ float ylinLds[BROWS];
    __shared__ float lwLds[FDIM];

    const int t    = threadIdx.x;
    const int lane = t & 63;
    const int wv   = t >> 6;
    const int hi   = lane >> 5;    // k-half (and num/den role)
    const int col  = lane & 31;    // batch col (B) / D-row index for A
    const int b0   = blockIdx.x * BROWS;

    if (t < FDIM) lwLds[t] = lin_w[t];

    // zero the pad row (f = 50)
    if (t < 64) {
        half8v z;
        #pragma unroll
        for (int e = 0; e < 8; ++e) z[e] = (_Float16)0;
        *(half8v*)&embLds[FDIM * 512 + t * 8] = z;
    }

    // ---- stage emb: lane l -> (b=l&31, kh=l>>5) ----
    for (int f = t >> 6; f < FDIM; f += NWAVE) {
        int   fi = feat_index[(b0 + col) * FDIM + f];
        float fv = feat_value[(b0 + col) * FDIM + f];
        const float4* tr = (const float4*)(emb_table + (size_t)fi * EDIM + hi * 8);
        float4 v0 = tr[0], v1 = tr[1];
        half8v hh;
        hh[0] = (_Float16)(v0.x * fv); hh[1] = (_Float16)(v0.y * fv);
        hh[2] = (_Float16)(v0.z * fv); hh[3] = (_Float16)(v0.w * fv);
        hh[4] = (_Float16)(v1.x * fv); hh[5] = (_Float16)(v1.y * fv);
        hh[6] = (_Float16)(v1.z * fv); hh[7] = (_Float16)(v1.w * fv);
        *(half8v*)&embLds[f * 512 + lane * 8] = hh;
    }
    __syncthreads();

    // ---- y_lin: threads 0..511: b = t>>4, e = t&15 ----
    if (t < 512) {
        int bb = t >> 4, e = t & 15;
        int off = (e >> 3) * 256 + bb * 8 + (e & 7);
        float acc = lin_b[0];
        #pragma unroll
        for (int f = 0; f < FDIM; ++f)
            acc = fmaf((float)embLds[f * 512 + off], lwLds[f], acc);
        acc = fmaxf(acc, 0.0f);
        acc += __shfl_xor(acc, 1);
        acc += __shfl_xor(acc, 2);
        acc += __shfl_xor(acc, 4);
        acc += __shfl_xor(acc, 8);
        if (e == 0) ylinLds[bb] = acc;
    }

    // ---- loop-invariant fragments ----
    // MFMA1: D[m][b] = sum_e A[m][e]*ewp[e][b] (+C). A rows: m<16 -> W^T, m==16 -> p, else 0.
    half8v fragA1;
    #pragma unroll
    for (int e = 0; e < 8; ++e) {
        int k = hi * 8 + e;
        float av = (col < ADIM) ? attn_w[k * ADIM + col]
                 : (col == ADIM) ? attn_p[k] : 0.0f;
        fragA1[e] = (_Float16)av;
    }
    // C/D row map: reg r (0..7) holds row (r&3)+8*(r>>2)+4*hi.
    // MFMA2: B2 elem e = packed relu(acc1[e]) = P[pi(k)][b], pi(k)=(e&3)+8*(e>>2)+4*hi
    //        -> A2[m][k] = h[pi(k)]*log2e for all m. C reuses biasC:
    //        acc2[0] = s + attn_b[4hi]; constant factor removed by corr at epilogue.
    half8v fragA2;
    f32x16 biasC;
    #pragma unroll
    for (int e = 0; e < 8; ++e) {
        int r = (e & 3) + 8 * (e >> 2) + 4 * hi;
        fragA2[e]  = (_Float16)(attn_h[r] * 1.44269504f);
        biasC[e]   = attn_b[r];
        biasC[e+8] = 0.f;
    }
    const float corr = __builtin_amdgcn_exp2f(-attn_b[4 * hi]);

    const char* ebase = (const char*)embLds;
    const unsigned laddr = (unsigned)lane * 16u;

    // ---- contiguous chunk: pairs [pbeg, pend), analytic i-run walk ----
    const int pbeg = wv * CHUNK;
    const int pend = (pbeg + CHUNK < NPAIR) ? pbeg + CHUNK : NPAIR;

    // decode (i,j) at pbeg (once per wave, wave-uniform)
    float tq = 9801.0f - 8.0f * (float)pbeg;
    int i = (int)((99.0f - sqrtf(tq)) * 0.5f);
    i = max(0, min(48, i));
    while (i < 48 && (49*(i+1) - (((i+1)*i)>>1)) <= pbeg) ++i;
    while (i > 0  && (49*i - ((i*(i-1))>>1)) > pbeg) --i;
    int j = i + 1 + (pbeg - (49*i - ((i*(i-1))>>1)));

    float num = 0.f, den = 0.f;
    int p = pbeg;
    while (p < pend) {                       // segment loop: one i-run per pass
        int len = FDIM - j;
        if (len > pend - p) len = pend - p;
        half8v ei = *(const half8v*)(ebase + (unsigned)(i * FBLK) + laddr);
        unsigned aj = (unsigned)(j * FBLK) + laddr;

        for (int n = 0; n < len; n += 2) {
            // two j's per body: fully independent chains (ILP)
            half8v ej0 = *(const half8v*)(ebase + aj);
            half8v ej1 = *(const half8v*)(ebase + aj + FBLK);   // may hit pad/next row
            aj += 2 * FBLK;
            float m1 = (n + 1 < len) ? 1.0f : 0.0f;              // wave-uniform gate

            half8v prod0 = ei * ej0;
            half8v prod1 = ei * ej1;
            f32x16 a10 = mfma32x32x16f16(fragA1, prod0, biasC);
            f32x16 a11 = mfma32x32x16f16(fragA1, prod1, biasC);
            half8v rf0 = relu_pack(a10);
            half8v rf1 = relu_pack(a11);
            f32x16 a20 = mfma32x32x16f16(fragA2, rf0, biasC);
            f32x16 a21 = mfma32x32x16f16(fragA2, rf1, biasC);
            float sc0 = __builtin_amdgcn_exp2f(a20[0]);
            float sc1 = __builtin_amdgcn_exp2f(a21[0]) * m1;
            den += sc0 + sc1;                        // valid on hi=1 lanes
            num = fmaf(sc0, a10[8], num);            // a1x[8]=u (hi=0); =0 (hi=1)
            num = fmaf(sc1, a11[8], num);
        }
        p += len;
        ++i;
        j = i + 1;
    }

    num *= corr;                        // undo the 2^attn_b[4hi] factor
    den *= corr;
    if (hi) redLds[wv][col][1] = den;   // hi=1 lanes: true denominator
    else    redLds[wv][col][0] = num;   // hi=0 lanes: true numerator
    __syncthreads();

    if (t < BROWS) {
        float nn = 0.f, dd = 0.f;
        #pragma unroll
        for (int w = 0; w < NWAVE; ++w) { nn += redLds[w][t][0]; dd += redLds[w][t][1]; }
        out[b0 + t] = nn / dd + ylinLds[t];
    }
}

extern "C" void kernel_launch(void* const* d_in, const int* in_sizes, int n_in,
                              void* d_out, int out_size, void* d_ws, size_t ws_size,
                              hipStream_t stream) {
    const int*   feat_index = (const int*)  d_in[0];
    const float* feat_value = (const float*)d_in[1];
    const float* emb_table  = (const float*)d_in[2];
    const float* attn_w     = (const float*)d_in[3];
    const float* attn_b     = (const float*)d_in[4];
    const float* attn_h     = (const float*)d_in[5];
    const float* attn_p     = (const float*)d_in[6];
    const float* lin_w      = (const float*)d_in[7];
    const float* lin_b      = (const float*)d_in[8];
    float* outp = (float*)d_out;

    dim3 grid(out_size / BROWS);   // 256 blocks of 32 batch rows
    dim3 block(NTHREADS);
    afm_fwd<<<grid, block, 0, stream>>>(feat_index, feat_value, emb_table,
                                        attn_w, attn_b, attn_h, attn_p,
                                        lin_w, lin_b, outp);
}

// Round 15
// 25.624 us; speedup vs baseline: 1.1425x; 1.1051x over previous
//
#include <hip/hip_runtime.h>
#include <math.h>

#define FDIM  50
#define EDIM  16
#define ADIM  16
#define NPAIR 1225
#define BROWS 32        // batch rows per block (MFMA cols)
#define NTHREADS 1024
#define NWAVE 16
#define CHUNK 77        // contiguous pairs per wave (last wave: 70)
#define FBLK  1024      // bytes per f-row in LDS: [lane64][16B]

typedef _Float16 half8v __attribute__((ext_vector_type(8)));
typedef __fp16   h16x8  __attribute__((ext_vector_type(8)));
typedef __fp16   h16x2  __attribute__((ext_vector_type(2)));
typedef float    f32x16 __attribute__((ext_vector_type(16)));

__device__ inline f32x16 mfma32x32x16f16(half8v a, half8v b, f32x16 c) {
    return __builtin_amdgcn_mfma_f32_32x32x16_f16(
        __builtin_bit_cast(h16x8, a), __builtin_bit_cast(h16x8, b), c, 0, 0, 0);
}

// verified relu+pack: 4x cvt_pkrtz + 4x v_pk_max_f16
__device__ inline half8v relu_pack(const f32x16& acc1) {
    h16x2 q01 = __builtin_amdgcn_cvt_pkrtz(acc1[0], acc1[1]);
    h16x2 q23 = __builtin_amdgcn_cvt_pkrtz(acc1[2], acc1[3]);
    h16x2 q45 = __builtin_amdgcn_cvt_pkrtz(acc1[4], acc1[5]);
    h16x2 q67 = __builtin_amdgcn_cvt_pkrtz(acc1[6], acc1[7]);
    h16x8 pk = __builtin_shufflevector(
                   __builtin_shufflevector(q01, q23, 0, 1, 2, 3),
                   __builtin_shufflevector(q45, q67, 0, 1, 2, 3),
                   0, 1, 2, 3, 4, 5, 6, 7);
    half8v rf = __builtin_bit_cast(half8v, pk);
    half8v zf;
    #pragma unroll
    for (int e = 0; e < 8; ++e) zf[e] = (_Float16)0;
    return __builtin_elementwise_max(rf, zf);
}

__global__ __launch_bounds__(NTHREADS) void afm_fwd(
    const int*   __restrict__ feat_index,
    const float* __restrict__ feat_value,
    const float* __restrict__ emb_table,
    const float* __restrict__ attn_w,
    const float* __restrict__ attn_b,
    const float* __restrict__ attn_h,
    const float* __restrict__ attn_p,
    const float* __restrict__ lin_w,
    const float* __restrict__ lin_b,
    float*       __restrict__ out)
{
    // [f][lane64][8 f16]: lane = kh*32 + b, holds e = kh*8..kh*8+7 for batch col b
    __shared__ __align__(16) _Float16 embLds[FDIM * 512];   // 51200 B
    __shared__ float redLds[NWAVE][BROWS][2];               // [wv][b][{num,den}]
    __shared__ float ylinLds[BROWS];
    __shared__ float lwLds[FDIM];

    const int t    = threadIdx.x;
    const int lane = t & 63;
    const int wv   = t >> 6;
    const int hi   = lane >> 5;    // k-half (and num/den role)
    const int col  = lane & 31;    // batch col (B) / D-row index for A
    const int b0   = blockIdx.x * BROWS;

    if (t < FDIM) lwLds[t] = lin_w[t];

    // ---- stage emb: lane l -> (b=l&31, kh=l>>5) ----
    for (int f = t >> 6; f < FDIM; f += NWAVE) {
        int   fi = feat_index[(b0 + col) * FDIM + f];
        float fv = feat_value[(b0 + col) * FDIM + f];
        const float4* tr = (const float4*)(emb_table + (size_t)fi * EDIM + hi * 8);
        float4 v0 = tr[0], v1 = tr[1];
        half8v hh;
        hh[0] = (_Float16)(v0.x * fv); hh[1] = (_Float16)(v0.y * fv);
        hh[2] = (_Float16)(v0.z * fv); hh[3] = (_Float16)(v0.w * fv);
        hh[4] = (_Float16)(v1.x * fv); hh[5] = (_Float16)(v1.y * fv);
        hh[6] = (_Float16)(v1.z * fv); hh[7] = (_Float16)(v1.w * fv);
        *(half8v*)&embLds[f * 512 + lane * 8] = hh;
    }
    __syncthreads();

    // ---- y_lin: threads 0..511: b = t>>4, e = t&15 ----
    if (t < 512) {
        int bb = t >> 4, e = t & 15;
        int off = (e >> 3) * 256 + bb * 8 + (e & 7);
        float acc = lin_b[0];
        #pragma unroll
        for (int f = 0; f < FDIM; ++f)
            acc = fmaf((float)embLds[f * 512 + off], lwLds[f], acc);
        acc = fmaxf(acc, 0.0f);
        acc += __shfl_xor(acc, 1);
        acc += __shfl_xor(acc, 2);
        acc += __shfl_xor(acc, 4);
        acc += __shfl_xor(acc, 8);
        if (e == 0) ylinLds[bb] = acc;
    }

    // ---- loop-invariant fragments ----
    // MFMA1: D[m][b] = sum_e A[m][e]*ewp[e][b] (+C). A rows: m<16 -> W^T, m==16 -> p, else 0.
    // Per i-run we fold diag(ei): fragA1r = fragA1 * ei, then B = ej directly.
    half8v fragA1;
    #pragma unroll
    for (int e = 0; e < 8; ++e) {
        int k = hi * 8 + e;
        float av = (col < ADIM) ? attn_w[k * ADIM + col]
                 : (col == ADIM) ? attn_p[k] : 0.0f;
        fragA1[e] = (_Float16)av;
    }
    // C/D row map: reg r (0..7) holds row (r&3)+8*(r>>2)+4*hi.
    // MFMA2: B2 elem e = packed relu(acc1[e]) = P[pi(k)][b], pi(k)=(e&3)+8*(e>>2)+4*hi
    //        -> A2[m][k] = h[pi(k)]*log2e for all m. C reuses biasC:
    //        acc2[0] = s + attn_b[4hi]; constant factor removed by corr at epilogue.
    half8v fragA2;
    f32x16 biasC;
    #pragma unroll
    for (int e = 0; e < 8; ++e) {
        int r = (e & 3) + 8 * (e >> 2) + 4 * hi;
        fragA2[e]  = (_Float16)(attn_h[r] * 1.44269504f);
        biasC[e]   = attn_b[r];
        biasC[e+8] = 0.f;
    }
    const float corr = __builtin_amdgcn_exp2f(-attn_b[4 * hi]);

    const char* ebase = (const char*)embLds;
    const unsigned laddr = (unsigned)lane * 16u;

    // ---- contiguous chunk: pairs [pbeg, pend), analytic i-run walk ----
    const int pbeg = wv * CHUNK;
    const int pend = (pbeg + CHUNK < NPAIR) ? pbeg + CHUNK : NPAIR;

    // decode (i,j) at pbeg (once per wave, wave-uniform)
    float tq = 9801.0f - 8.0f * (float)pbeg;
    int i = (int)((99.0f - sqrtf(tq)) * 0.5f);
    i = max(0, min(48, i));
    while (i < 48 && (49*(i+1) - (((i+1)*i)>>1)) <= pbeg) ++i;
    while (i > 0  && (49*i - ((i*(i-1))>>1)) > pbeg) --i;
    int j = i + 1 + (pbeg - (49*i - ((i*(i-1))>>1)));

    float num0 = 0.f, num1 = 0.f, den0 = 0.f, den1 = 0.f;
    int p = pbeg;
    while (p < pend) {                       // segment loop: one i-run per pass
        int len = FDIM - j;
        if (len > pend - p) len = pend - p;
        half8v ei = *(const half8v*)(ebase + (unsigned)(i * FBLK) + laddr);
        half8v fragA1r = fragA1 * ei;        // fold diag(ei) into A (4 pk_mul / run)
        unsigned aj = (unsigned)(j * FBLK) + laddr;

        int ndual = len >> 1;
        #pragma unroll 2
        for (int n = 0; n < ndual; ++n) {
            half8v ej0 = *(const half8v*)(ebase + aj);
            half8v ej1 = *(const half8v*)(ebase + aj + FBLK);
            aj += 2 * FBLK;

            f32x16 a10 = mfma32x32x16f16(fragA1r, ej0, biasC);
            f32x16 a11 = mfma32x32x16f16(fragA1r, ej1, biasC);
            half8v rf0 = relu_pack(a10);
            half8v rf1 = relu_pack(a11);
            f32x16 a20 = mfma32x32x16f16(fragA2, rf0, biasC);
            f32x16 a21 = mfma32x32x16f16(fragA2, rf1, biasC);
            float sc0 = __builtin_amdgcn_exp2f(a20[0]);
            float sc1 = __builtin_amdgcn_exp2f(a21[0]);
            den0 += sc0;                              // valid on hi=1 lanes
            den1 += sc1;
            num0 = fmaf(sc0, a10[8], num0);           // a1x[8]=u (hi=0); =0 (hi=1)
            num1 = fmaf(sc1, a11[8], num1);
        }
        if (len & 1) {                                // odd tail of the run
            half8v ej0 = *(const half8v*)(ebase + aj);
            f32x16 a10 = mfma32x32x16f16(fragA1r, ej0, biasC);
            half8v rf0 = relu_pack(a10);
            f32x16 a20 = mfma32x32x16f16(fragA2, rf0, biasC);
            float sc0 = __builtin_amdgcn_exp2f(a20[0]);
            den0 += sc0;
            num0 = fmaf(sc0, a10[8], num0);
        }
        p += len;
        ++i;
        j = i + 1;
    }

    float num = (num0 + num1) * corr;   // undo the 2^attn_b[4hi] factor
    float den = (den0 + den1) * corr;
    if (hi) redLds[wv][col][1] = den;   // hi=1 lanes: true denominator
    else    redLds[wv][col][0] = num;   // hi=0 lanes: true numerator
    __syncthreads();

    if (t < BROWS) {
        float nn = 0.f, dd = 0.f;
        #pragma unroll
        for (int w = 0; w < NWAVE; ++w) { nn += redLds[w][t][0]; dd += redLds[w][t][1]; }
        out[b0 + t] = nn / dd + ylinLds[t];
    }
}

extern "C" void kernel_launch(void* const* d_in, const int* in_sizes, int n_in,
                              void* d_out, int out_size, void* d_ws, size_t ws_size,
                              hipStream_t stream) {
    const int*   feat_index = (const int*)  d_in[0];
    const float* feat_value = (const float*)d_in[1];
    const float* emb_table  = (const float*)d_in[2];
    const float* attn_w     = (const float*)d_in[3];
    const float* attn_b     = (const float*)d_in[4];
    const float* attn_h     = (const float*)d_in[5];
    const float* attn_p     = (const float*)d_in[6];
    const float* lin_w      = (const float*)d_in[7];
    const float* lin_b      = (const float*)d_in[8];
    float* outp = (float*)d_out;

    dim3 grid(out_size / BROWS);   // 256 blocks of 32 batch rows
    dim3 block(NTHREADS);
    afm_fwd<<<grid, block, 0, stream>>>(feat_index, feat_value, emb_table,
                                        attn_w, attn_b, attn_h, attn_p,
                                        lin_w, lin_b, outp);
}

// Round 16
// 25.595 us; speedup vs baseline: 1.1438x; 1.0012x over previous
//
#include <hip/hip_runtime.h>
#include <math.h>

#define FDIM  50
#define EDIM  16
#define ADIM  16
#define NPAIR 1225
#define BROWS 32        // batch rows per block (MFMA cols)
#define NTHREADS 1024
#define NWAVE 16
#define CHUNK 77        // contiguous pairs per wave (last wave: 70)
#define FBLK  1024      // bytes per f-row in LDS: [lane64][16B]

typedef _Float16 half8v __attribute__((ext_vector_type(8)));
typedef __fp16   h16x8  __attribute__((ext_vector_type(8)));
typedef __fp16   h16x2  __attribute__((ext_vector_type(2)));
typedef float    f32x16 __attribute__((ext_vector_type(16)));

__device__ inline f32x16 mfma32x32x16f16(half8v a, half8v b, f32x16 c) {
    return __builtin_amdgcn_mfma_f32_32x32x16_f16(
        __builtin_bit_cast(h16x8, a), __builtin_bit_cast(h16x8, b), c, 0, 0, 0);
}

// verified relu+pack: 4x cvt_pkrtz + 4x v_pk_max_f16
__device__ inline half8v relu_pack(const f32x16& acc1) {
    h16x2 q01 = __builtin_amdgcn_cvt_pkrtz(acc1[0], acc1[1]);
    h16x2 q23 = __builtin_amdgcn_cvt_pkrtz(acc1[2], acc1[3]);
    h16x2 q45 = __builtin_amdgcn_cvt_pkrtz(acc1[4], acc1[5]);
    h16x2 q67 = __builtin_amdgcn_cvt_pkrtz(acc1[6], acc1[7]);
    h16x8 pk = __builtin_shufflevector(
                   __builtin_shufflevector(q01, q23, 0, 1, 2, 3),
                   __builtin_shufflevector(q45, q67, 0, 1, 2, 3),
                   0, 1, 2, 3, 4, 5, 6, 7);
    half8v rf = __builtin_bit_cast(half8v, pk);
    half8v zf;
    #pragma unroll
    for (int e = 0; e < 8; ++e) zf[e] = (_Float16)0;
    return __builtin_elementwise_max(rf, zf);
}

__global__ __launch_bounds__(NTHREADS) void afm_fwd(
    const int*   __restrict__ feat_index,
    const float* __restrict__ feat_value,
    const float* __restrict__ emb_table,
    const float* __restrict__ attn_w,
    const float* __restrict__ attn_b,
    const float* __restrict__ attn_h,
    const float* __restrict__ attn_p,
    const float* __restrict__ lin_w,
    const float* __restrict__ lin_b,
    float*       __restrict__ out)
{
    // [f][lane64][8 f16]: lane = kh*32 + b, holds e = kh*8..kh*8+7 for batch col b
    __shared__ __align__(16) _Float16 embLds[FDIM * 512];   // 51200 B
    __shared__ float redLds[NWAVE][BROWS][2];               // [wv][b][{num,den}]
    __shared__ float ylinLds[BROWS];
    __shared__ float lwLds[FDIM];

    const int t    = threadIdx.x;
    const int lane = t & 63;
    const int wv   = t >> 6;
    const int hi   = lane >> 5;    // k-half (and num/den role)
    const int col  = lane & 31;    // batch col (B) / D-row index for A
    const int b0   = blockIdx.x * BROWS;

    if (t < FDIM) lwLds[t] = lin_w[t];

    // ---- stage emb: lane l -> (b=l&31, kh=l>>5) ----
    for (int f = t >> 6; f < FDIM; f += NWAVE) {
        int   fi = feat_index[(b0 + col) * FDIM + f];
        float fv = feat_value[(b0 + col) * FDIM + f];
        const float4* tr = (const float4*)(emb_table + (size_t)fi * EDIM + hi * 8);
        float4 v0 = tr[0], v1 = tr[1];
        half8v hh;
        hh[0] = (_Float16)(v0.x * fv); hh[1] = (_Float16)(v0.y * fv);
        hh[2] = (_Float16)(v0.z * fv); hh[3] = (_Float16)(v0.w * fv);
        hh[4] = (_Float16)(v1.x * fv); hh[5] = (_Float16)(v1.y * fv);
        hh[6] = (_Float16)(v1.z * fv); hh[7] = (_Float16)(v1.w * fv);
        *(half8v*)&embLds[f * 512 + lane * 8] = hh;
    }
    __syncthreads();

    // ---- y_lin: threads 0..511: b = t>>4, e = t&15 ----
    if (t < 512) {
        int bb = t >> 4, e = t & 15;
        int off = (e >> 3) * 256 + bb * 8 + (e & 7);
        float acc = lin_b[0];
        #pragma unroll
        for (int f = 0; f < FDIM; ++f)
            acc = fmaf((float)embLds[f * 512 + off], lwLds[f], acc);
        acc = fmaxf(acc, 0.0f);
        acc += __shfl_xor(acc, 1);
        acc += __shfl_xor(acc, 2);
        acc += __shfl_xor(acc, 4);
        acc += __shfl_xor(acc, 8);
        if (e == 0) ylinLds[bb] = acc;
    }

    // ---- loop-invariant fragments ----
    // MFMA1: D[m][b] = sum_e A[m][e]*ewp[e][b] (+C). A rows: m<16 -> W^T, m==16 -> p, else 0.
    // Per i-run we fold diag(ei): fragA1r = fragA1 * ei, then B = ej directly.
    half8v fragA1;
    #pragma unroll
    for (int e = 0; e < 8; ++e) {
        int k = hi * 8 + e;
        float av = (col < ADIM) ? attn_w[k * ADIM + col]
                 : (col == ADIM) ? attn_p[k] : 0.0f;
        fragA1[e] = (_Float16)av;
    }
    // C/D row map: reg r (0..7) holds row (r&3)+8*(r>>2)+4*hi; reg 8 -> row 16+4*hi.
    // MFMA2: B2 elem e = packed relu(acc1[e]) = P[pi(k)][b], pi(k)=(e&3)+8*(e>>2)+4*hi
    //        -> A2[m][k] = h[pi(k)]*log2e for all m. C reuses biasC:
    //        acc2[0] = s + attn_b[4hi]; constant factor removed by corr at epilogue.
    // biasC[8] = hi: acc1[8] = u (hi=0, row16=p) or exactly 1 (hi=1, row20=0 + C)
    //        -> single accumulator acc = fmaf(sc, acc1[8], acc) serves num AND den.
    half8v fragA2;
    f32x16 biasC;
    #pragma unroll
    for (int e = 0; e < 8; ++e) {
        int r = (e & 3) + 8 * (e >> 2) + 4 * hi;
        fragA2[e]  = (_Float16)(attn_h[r] * 1.44269504f);
        biasC[e]   = attn_b[r];
        biasC[e+8] = 0.f;
    }
    biasC[8] = hi ? 1.0f : 0.0f;
    const float corr = __builtin_amdgcn_exp2f(-attn_b[4 * hi]);

    const char* ebase = (const char*)embLds;
    const unsigned laddr = (unsigned)lane * 16u;

    // ---- contiguous chunk: pairs [pbeg, pend), analytic i-run walk ----
    const int pbeg = wv * CHUNK;
    const int pend = (pbeg + CHUNK < NPAIR) ? pbeg + CHUNK : NPAIR;

    // decode (i,j) at pbeg (once per wave, wave-uniform)
    float tq = 9801.0f - 8.0f * (float)pbeg;
    int i = (int)((99.0f - sqrtf(tq)) * 0.5f);
    i = max(0, min(48, i));
    while (i < 48 && (49*(i+1) - (((i+1)*i)>>1)) <= pbeg) ++i;
    while (i > 0  && (49*i - ((i*(i-1))>>1)) > pbeg) --i;
    int j = i + 1 + (pbeg - (49*i - ((i*(i-1))>>1)));

    float accA = 0.f, accB = 0.f;       // unified num/den accumulators (role by hi)
    int p = pbeg;
    while (p < pend) {                  // segment loop: one i-run per pass
        int len = FDIM - j;
        if (len > pend - p) len = pend - p;
        half8v ei = *(const half8v*)(ebase + (unsigned)(i * FBLK) + laddr);
        half8v fragA1r = fragA1 * ei;   // fold diag(ei) into A (4 pk_mul / run)
        unsigned aj = (unsigned)(j * FBLK) + laddr;

        int ndual = len >> 1;
        #pragma unroll 2
        for (int n = 0; n < ndual; ++n) {
            half8v ej0 = *(const half8v*)(ebase + aj);
            half8v ej1 = *(const half8v*)(ebase + aj + FBLK);
            aj += 2 * FBLK;

            f32x16 a10 = mfma32x32x16f16(fragA1r, ej0, biasC);
            f32x16 a11 = mfma32x32x16f16(fragA1r, ej1, biasC);
            half8v rf0 = relu_pack(a10);
            half8v rf1 = relu_pack(a11);
            f32x16 a20 = mfma32x32x16f16(fragA2, rf0, biasC);
            f32x16 a21 = mfma32x32x16f16(fragA2, rf1, biasC);
            float sc0 = __builtin_amdgcn_exp2f(a20[0]);
            float sc1 = __builtin_amdgcn_exp2f(a21[0]);
            accA = fmaf(sc0, a10[8], accA);   // hi=0: += sc*u ; hi=1: += sc*1
            accB = fmaf(sc1, a11[8], accB);
        }
        if (len & 1) {                         // odd tail of the run
            half8v ej0 = *(const half8v*)(ebase + aj);
            f32x16 a10 = mfma32x32x16f16(fragA1r, ej0, biasC);
            half8v rf0 = relu_pack(a10);
            f32x16 a20 = mfma32x32x16f16(fragA2, rf0, biasC);
            float sc0 = __builtin_amdgcn_exp2f(a20[0]);
            accA = fmaf(sc0, a10[8], accA);
        }
        p += len;
        ++i;
        j = i + 1;
    }

    float acc = (accA + accB) * corr;   // undo the 2^attn_b[4hi] factor
    if (hi) redLds[wv][col][1] = acc;   // hi=1 lanes: denominator
    else    redLds[wv][col][0] = acc;   // hi=0 lanes: numerator
    __syncthreads();

    if (t < BROWS) {
        float nn = 0.f, dd = 0.f;
        #pragma unroll
        for (int w = 0; w < NWAVE; ++w) { nn += redLds[w][t][0]; dd += redLds[w][t][1]; }
        out[b0 + t] = nn / dd + ylinLds[t];
    }
}

extern "C" void kernel_launch(void* const* d_in, const int* in_sizes, int n_in,
                              void* d_out, int out_size, void* d_ws, size_t ws_size,
                              hipStream_t stream) {
    const int*   feat_index = (const int*)  d_in[0];
    const float* feat_value = (const float*)d_in[1];
    const float* emb_table  = (const float*)d_in[2];
    const float* attn_w     = (const float*)d_in[3];
    const float* attn_b     = (const float*)d_in[4];
    const float* attn_h     = (const float*)d_in[5];
    const float* attn_p     = (const float*)d_in[6];
    const float* lin_w      = (const float*)d_in[7];
    const float* lin_b      = (const float*)d_in[8];
    float* outp = (float*)d_out;

    dim3 grid(out_size / BROWS);   // 256 blocks of 32 batch rows
    dim3 block(NTHREADS);
    afm_fwd<<<grid, block, 0, stream>>>(feat_index, feat_value, emb_table,
                                        attn_w, attn_b, attn_h, attn_p,
                                        lin_w, lin_b, outp);
}

// Round 17
// 25.517 us; speedup vs baseline: 1.1473x; 1.0031x over previous
//
#include <hip/hip_runtime.h>
#include <math.h>

#define FDIM  50
#define EDIM  16
#define ADIM  16
#define NPAIR 1225
#define BROWS 32        // batch rows per block (MFMA cols)
#define NTHREADS 1024
#define NWAVE 16
#define CHUNK 77        // contiguous pairs per wave (last wave: 70)
#define FBLK  1024      // bytes per f-row in LDS: [lane64][16B]

typedef _Float16 half8v __attribute__((ext_vector_type(8)));
typedef __fp16   h16x8  __attribute__((ext_vector_type(8)));
typedef __fp16   h16x2  __attribute__((ext_vector_type(2)));
typedef float    f32x16 __attribute__((ext_vector_type(16)));

__device__ inline f32x16 mfma32x32x16f16(half8v a, half8v b, f32x16 c) {
    return __builtin_amdgcn_mfma_f32_32x32x16_f16(
        __builtin_bit_cast(h16x8, a), __builtin_bit_cast(h16x8, b), c, 0, 0, 0);
}

// verified relu+pack: 4x cvt_pkrtz + 4x v_pk_max_f16
__device__ inline half8v relu_pack(const f32x16& acc1) {
    h16x2 q01 = __builtin_amdgcn_cvt_pkrtz(acc1[0], acc1[1]);
    h16x2 q23 = __builtin_amdgcn_cvt_pkrtz(acc1[2], acc1[3]);
    h16x2 q45 = __builtin_amdgcn_cvt_pkrtz(acc1[4], acc1[5]);
    h16x2 q67 = __builtin_amdgcn_cvt_pkrtz(acc1[6], acc1[7]);
    h16x8 pk = __builtin_shufflevector(
                   __builtin_shufflevector(q01, q23, 0, 1, 2, 3),
                   __builtin_shufflevector(q45, q67, 0, 1, 2, 3),
                   0, 1, 2, 3, 4, 5, 6, 7);
    half8v rf = __builtin_bit_cast(half8v, pk);
    half8v zf;
    #pragma unroll
    for (int e = 0; e < 8; ++e) zf[e] = (_Float16)0;
    return __builtin_elementwise_max(rf, zf);
}

__global__ __launch_bounds__(NTHREADS) void afm_fwd(
    const int*   __restrict__ feat_index,
    const float* __restrict__ feat_value,
    const float* __restrict__ emb_table,
    const float* __restrict__ attn_w,
    const float* __restrict__ attn_b,
    const float* __restrict__ attn_h,
    const float* __restrict__ attn_p,
    const float* __restrict__ lin_w,
    const float* __restrict__ lin_b,
    float*       __restrict__ out)
{
    // [f][lane64][8 f16]: lane = kh*32 + b, holds e = kh*8..kh*8+7 for batch col b
    __shared__ __align__(16) _Float16 embLds[FDIM * 512];   // 51200 B
    __shared__ float redLds[NWAVE][BROWS][2];               // [wv][b][{num,den}]
    __shared__ float ylinLds[BROWS];
    __shared__ float lwLds[FDIM];

    const int t    = threadIdx.x;
    const int lane = t & 63;
    const int wv   = t >> 6;
    const int hi   = lane >> 5;    // k-half (and num/den role)
    const int col  = lane & 31;    // batch col (B) / D-row index for A
    const int b0   = blockIdx.x * BROWS;

    if (t < FDIM) lwLds[t] = lin_w[t];

    // ---- stage emb: lane l -> (b=l&31, kh=l>>5) ----
    for (int f = t >> 6; f < FDIM; f += NWAVE) {
        int   fi = feat_index[(b0 + col) * FDIM + f];
        float fv = feat_value[(b0 + col) * FDIM + f];
        const float4* tr = (const float4*)(emb_table + (size_t)fi * EDIM + hi * 8);
        float4 v0 = tr[0], v1 = tr[1];
        half8v hh;
        hh[0] = (_Float16)(v0.x * fv); hh[1] = (_Float16)(v0.y * fv);
        hh[2] = (_Float16)(v0.z * fv); hh[3] = (_Float16)(v0.w * fv);
        hh[4] = (_Float16)(v1.x * fv); hh[5] = (_Float16)(v1.y * fv);
        hh[6] = (_Float16)(v1.z * fv); hh[7] = (_Float16)(v1.w * fv);
        *(half8v*)&embLds[f * 512 + lane * 8] = hh;
    }
    __syncthreads();

    // ---- y_lin: threads 0..511: b = t>>4, e = t&15 ----
    if (t < 512) {
        int bb = t >> 4, e = t & 15;
        int off = (e >> 3) * 256 + bb * 8 + (e & 7);
        float acc = lin_b[0];
        #pragma unroll
        for (int f = 0; f < FDIM; ++f)
            acc = fmaf((float)embLds[f * 512 + off], lwLds[f], acc);
        acc = fmaxf(acc, 0.0f);
        acc += __shfl_xor(acc, 1);
        acc += __shfl_xor(acc, 2);
        acc += __shfl_xor(acc, 4);
        acc += __shfl_xor(acc, 8);
        if (e == 0) ylinLds[bb] = acc;
    }

    // ---- loop-invariant fragments ----
    half8v fragA1;
    #pragma unroll
    for (int e = 0; e < 8; ++e) {
        int k = hi * 8 + e;
        float av = (col < ADIM) ? attn_w[k * ADIM + col]
                 : (col == ADIM) ? attn_p[k] : 0.0f;
        fragA1[e] = (_Float16)av;
    }
    // C/D row map: reg r (0..7) -> row (r&3)+8*(r>>2)+4*hi; reg 8 -> row 16+4*hi.
    // MFMA2: A2[m][k] = h[pi(k)]*log2e, pi(k)=(e&3)+8*(e>>2)+4*hi; C reuses biasC.
    // biasC[8] = hi: acc1[8] = u (hi=0) or exactly 1 (hi=1) -> unified accumulator.
    half8v fragA2;
    f32x16 biasC;
    #pragma unroll
    for (int e = 0; e < 8; ++e) {
        int r = (e & 3) + 8 * (e >> 2) + 4 * hi;
        fragA2[e]  = (_Float16)(attn_h[r] * 1.44269504f);
        biasC[e]   = attn_b[r];
        biasC[e+8] = 0.f;
    }
    biasC[8] = hi ? 1.0f : 0.0f;
    const float corr = __builtin_amdgcn_exp2f(-attn_b[4 * hi]);

    const char* ebase = (const char*)embLds;
    const unsigned laddr = (unsigned)lane * 16u;

    // ---- contiguous chunk: pairs [pbeg, pend), analytic i-run walk ----
    const int pbeg = wv * CHUNK;
    const int pend = (pbeg + CHUNK < NPAIR) ? pbeg + CHUNK : NPAIR;

    float tq = 9801.0f - 8.0f * (float)pbeg;
    int i = (int)((99.0f - sqrtf(tq)) * 0.5f);
    i = max(0, min(48, i));
    while (i < 48 && (49*(i+1) - (((i+1)*i)>>1)) <= pbeg) ++i;
    while (i > 0  && (49*i - ((i*(i-1))>>1)) > pbeg) --i;
    int j = i + 1 + (pbeg - (49*i - ((i*(i-1))>>1)));

    float acc0 = 0.f, acc1s = 0.f, acc2s = 0.f, acc3s = 0.f;
    int p = pbeg;
    while (p < pend) {                  // segment loop: one i-run per pass
        int len = FDIM - j;
        if (len > pend - p) len = pend - p;
        half8v ei = *(const half8v*)(ebase + (unsigned)(i * FBLK) + laddr);
        half8v fragA1r = fragA1 * ei;   // fold diag(ei) into A (4 pk_mul / run)
        unsigned aj = (unsigned)(j * FBLK) + laddr;

        int nquad = len >> 2;
        for (int n = 0; n < nquad; ++n) {
            // 4 independent chains
            half8v ej0 = *(const half8v*)(ebase + aj);
            half8v ej1 = *(const half8v*)(ebase + aj + FBLK);
            half8v ej2 = *(const half8v*)(ebase + aj + 2 * FBLK);
            half8v ej3 = *(const half8v*)(ebase + aj + 3 * FBLK);
            aj += 4 * FBLK;

            f32x16 a10 = mfma32x32x16f16(fragA1r, ej0, biasC);
            f32x16 a11 = mfma32x32x16f16(fragA1r, ej1, biasC);
            f32x16 a12 = mfma32x32x16f16(fragA1r, ej2, biasC);
            f32x16 a13 = mfma32x32x16f16(fragA1r, ej3, biasC);
            half8v rf0 = relu_pack(a10);
            half8v rf1 = relu_pack(a11);
            half8v rf2 = relu_pack(a12);
            half8v rf3 = relu_pack(a13);
            f32x16 a20 = mfma32x32x16f16(fragA2, rf0, biasC);
            f32x16 a21 = mfma32x32x16f16(fragA2, rf1, biasC);
            f32x16 a22 = mfma32x32x16f16(fragA2, rf2, biasC);
            f32x16 a23 = mfma32x32x16f16(fragA2, rf3, biasC);
            float sc0 = __builtin_amdgcn_exp2f(a20[0]);
            float sc1 = __builtin_amdgcn_exp2f(a21[0]);
            float sc2 = __builtin_amdgcn_exp2f(a22[0]);
            float sc3 = __builtin_amdgcn_exp2f(a23[0]);
            acc0  = fmaf(sc0, a10[8], acc0);   // hi=0: += sc*u ; hi=1: += sc*1
            acc1s = fmaf(sc1, a11[8], acc1s);
            acc2s = fmaf(sc2, a12[8], acc2s);
            acc3s = fmaf(sc3, a13[8], acc3s);
        }
        int rem = len & 3;
        if (rem & 2) {                        // dual tail
            half8v ej0 = *(const half8v*)(ebase + aj);
            half8v ej1 = *(const half8v*)(ebase + aj + FBLK);
            aj += 2 * FBLK;
            f32x16 a10 = mfma32x32x16f16(fragA1r, ej0, biasC);
            f32x16 a11 = mfma32x32x16f16(fragA1r, ej1, biasC);
            half8v rf0 = relu_pack(a10);
            half8v rf1 = relu_pack(a11);
            f32x16 a20 = mfma32x32x16f16(fragA2, rf0, biasC);
            f32x16 a21 = mfma32x32x16f16(fragA2, rf1, biasC);
            float sc0 = __builtin_amdgcn_exp2f(a20[0]);
            float sc1 = __builtin_amdgcn_exp2f(a21[0]);
            acc0  = fmaf(sc0, a10[8], acc0);
            acc1s = fmaf(sc1, a11[8], acc1s);
        }
        if (rem & 1) {                        // single tail
            half8v ej0 = *(const half8v*)(ebase + aj);
            f32x16 a10 = mfma32x32x16f16(fragA1r, ej0, biasC);
            half8v rf0 = relu_pack(a10);
            f32x16 a20 = mfma32x32x16f16(fragA2, rf0, biasC);
            float sc0 = __builtin_amdgcn_exp2f(a20[0]);
            acc0 = fmaf(sc0, a10[8], acc0);
        }
        p += len;
        ++i;
        j = i + 1;
    }

    float acc = ((acc0 + acc1s) + (acc2s + acc3s)) * corr;
    if (hi) redLds[wv][col][1] = acc;   // hi=1 lanes: denominator
    else    redLds[wv][col][0] = acc;   // hi=0 lanes: numerator
    __syncthreads();

    if (t < BROWS) {
        float nn = 0.f, dd = 0.f;
        #pragma unroll
        for (int w = 0; w < NWAVE; ++w) { nn += redLds[w][t][0]; dd += redLds[w][t][1]; }
        out[b0 + t] = nn / dd + ylinLds[t];
    }
}

extern "C" void kernel_launch(void* const* d_in, const int* in_sizes, int n_in,
                              void* d_out, int out_size, void* d_ws, size_t ws_size,
                              hipStream_t stream) {
    const int*   feat_index = (const int*)  d_in[0];
    const float* feat_value = (const float*)d_in[1];
    const float* emb_table  = (const float*)d_in[2];
    const float* attn_w     = (const float*)d_in[3];
    const float* attn_b     = (const float*)d_in[4];
    const float* attn_h     = (const float*)d_in[5];
    const float* attn_p     = (const float*)d_in[6];
    const float* lin_w      = (const float*)d_in[7];
    const float* lin_b      = (const float*)d_in[8];
    float* outp = (float*)d_out;

    dim3 grid(out_size / BROWS);   // 256 blocks of 32 batch rows
    dim3 block(NTHREADS);
    afm_fwd<<<grid, block, 0, stream>>>(feat_index, feat_value, emb_table,
                                        attn_w, attn_b, attn_h, attn_p,
                                        lin_w, lin_b, outp);
}